// Round 1
// baseline (231.037 us; speedup 1.0000x reference)
//
#include <hip/hip_runtime.h>
#include <hip/hip_bf16.h>

// out[i, j] = x[i, j] * weight[j]
// x: 32768 x 1024 fp32, weight: 1024 fp32, out: 32768 x 1024 fp32.
// Memory-bound: 268 MB of HBM traffic, floor ~43 us at 6.3-6.8 TB/s.
//
// R0: plain float4/thread            -> bench 223.8 us (kernel component <79 us)
// R1: ILP x4                         -> bench 227.8 us (neutral)
// R2/R3: nontemporal load/store      -> bench 219.9 us
// R4 (this): persistent grid-stride over rows.
//   - Row is 1024 floats = 256 float4 = exactly one 256-thread block,
//     so each thread's weight value w4[threadIdx.x] is LOOP-INVARIANT:
//     loaded once into 4 VGPRs instead of 8.4M redundant cached loads
//     sharing the VMEM issue pipe with the x stream.
//   - grid = 2048 blocks x 4 waves = 8192 waves = exactly 256 CU x 32
//     wave slots: one dispatch round, no tail, 16 rows/thread.
//   - unroll x4 keeps 4 independent nontemporal loads in flight.

typedef float floatx4 __attribute__((ext_vector_type(4)));

__global__ __launch_bounds__(256) void diag_scale_kernel(
    const floatx4* __restrict__ x4,
    const floatx4* __restrict__ w4,   // 256 x4 = 1024 floats
    floatx4* __restrict__ out4,
    int nrows)
{
    const floatx4 wv = w4[threadIdx.x];          // loop-invariant column weight

    // Each block walks rows blockIdx.x, blockIdx.x+gridDim.x, ...
    int r = blockIdx.x;
    const int stride = gridDim.x;

#pragma unroll 4
    for (; r < nrows; r += stride) {
        const int idx = (r << 8) + threadIdx.x;  // r*256 float4 per row
        floatx4 xv = __builtin_nontemporal_load(&x4[idx]);
        __builtin_nontemporal_store(xv * wv, &out4[idx]);
    }
}

extern "C" void kernel_launch(void* const* d_in, const int* in_sizes, int n_in,
                              void* d_out, int out_size, void* d_ws, size_t ws_size,
                              hipStream_t stream) {
    const floatx4* x4 = (const floatx4*)d_in[0];
    const floatx4* w4 = (const floatx4*)d_in[1];
    floatx4* out4 = (floatx4*)d_out;

    const int nrows = out_size / 1024;   // 32768 rows (out_size is float count)
    const int grid  = 2048;              // 2048 x 4 waves = 8192 = 256 CU x 32 slots
    diag_scale_kernel<<<grid, 256, 0, stream>>>(x4, w4, out4, nrows);
}

// Round 2
// 219.499 us; speedup vs baseline: 1.0526x; 1.0526x over previous
//
#include <hip/hip_runtime.h>
#include <hip/hip_bf16.h>

// out[i, j] = x[i, j] * weight[j]
// x: 32768 x 1024 fp32, weight: 1024 fp32, out: 32768 x 1024 fp32.
// Memory-bound: 268 MB of HBM traffic, floor ~43 us at 6.3 TB/s copy BW.
//
// R0: plain float4/thread, 32768 blk    -> 223.8 us
// R1: ILP x4 (no NT)                    -> 227.8 us
// R2/R3: + nontemporal load/store       -> 219.9 us  (best)
// R4: persistent 2048-blk, 16-iter loop -> 231.0 us  REGRESSED
//     lesson: zero oversubscription (one resident round) -> stragglers;
//     this op wants max TLP + self-balancing small blocks.
// R5 (this): middle ground. 4 row-strided tiles per block, fully unrolled:
//   - weight w4[tid] loaded ONCE per thread (9 VMEM ops / 4 tiles vs 12)
//   - 4 independent NT loads in flight before first store (MLP=4)
//   - grid 8192 x 4 waves = 32768 waves = 4 full occupancy rounds ->
//     still oversubscribed, keeps the R0-style self-balancing R4 lost.

typedef float floatx4 __attribute__((ext_vector_type(4)));

__global__ __launch_bounds__(256) void diag_scale_kernel(
    const floatx4* __restrict__ x4,
    const floatx4* __restrict__ w4,   // 256 x4 = 1024 floats
    floatx4* __restrict__ out4)
{
    const floatx4 wv = w4[threadIdx.x];              // once per thread
    const int base = blockIdx.x * (4 * 256) + threadIdx.x;

    floatx4 a = __builtin_nontemporal_load(&x4[base]);
    floatx4 b = __builtin_nontemporal_load(&x4[base + 256]);
    floatx4 c = __builtin_nontemporal_load(&x4[base + 512]);
    floatx4 d = __builtin_nontemporal_load(&x4[base + 768]);

    __builtin_nontemporal_store(a * wv, &out4[base]);
    __builtin_nontemporal_store(b * wv, &out4[base + 256]);
    __builtin_nontemporal_store(c * wv, &out4[base + 512]);
    __builtin_nontemporal_store(d * wv, &out4[base + 768]);
}

extern "C" void kernel_launch(void* const* d_in, const int* in_sizes, int n_in,
                              void* d_out, int out_size, void* d_ws, size_t ws_size,
                              hipStream_t stream) {
    const floatx4* x4 = (const floatx4*)d_in[0];
    const floatx4* w4 = (const floatx4*)d_in[1];
    floatx4* out4 = (floatx4*)d_out;

    const int n4 = out_size / 4;          // 8388608 float4 tiles
    const int grid = n4 / (4 * 256);      // 8192 blocks, exact cover (no tail)
    diag_scale_kernel<<<grid, 256, 0, stream>>>(x4, w4, out4);
}